// Round 2
// baseline (76.053 us; speedup 1.0000x reference)
//
#include <hip/hip_runtime.h>
#include <hip/hip_bf16.h>
#include <math.h>

#define B_   4
#define T1_  4096
#define T2_  512
#define IC_  32
#define OC_  64
#define KS_  64

typedef unsigned short u16;
typedef unsigned int   u32;
typedef __attribute__((ext_vector_type(8))) short  short8;   // 8 bf16 = 4 VGPRs
typedef __attribute__((ext_vector_type(4))) float  float4v;  // MFMA C/D frag

#define PI_F 3.14159265358979323846f

// validated RNE fp32 -> bf16
__device__ __forceinline__ u16 f2bf(float f) {
    union { u32 u; float f; } v; v.f = f;
    u32 u = v.u;
    return (u16)((u + 0x7FFFu + ((u >> 16) & 1u)) >> 16);
}

// ---------------------------------------------------------------------------
// Fully fused kernel: 256 blocks x 512 threads (8 waves), 8 bt per block.
// Numeric path is bit-identical to the validated two-kernel pipeline
// (sinf/cosf + f2bf everywhere); only the plumbing is fused.
//
// Stage 1 (per wave, bt = blk*8 + w): Y_bt(64x32) = W(f)(64x64 circulant)
//   @ Xwin(64x32) via 16x16x32 bf16 MFMA (R7-validated math).
//   Y goes to LDS only, frag-ordered + swizzled:
//     byte(row, cs) = (cs>>3)*128 + ((row ^ ((cs>>6)&7))<<4) + (cs&7)*2
//   -> stage-2 ds_read_b128 conflict-free; stage-1 ds_write_b64 at the
//   4-cycle bank minimum. (Mapping verified bijective: 512 thr x 8 uint2
//   = 4096 slots = full 32 KB.)
//
// Stage 2: out[bt,o] = sum_cs Y[bt,cs]*bf16(kern[o][cs>>6][cs&63]) + bias.
//   M=16 MFMA, 8 real bt rows (rows 8-15 = broadcast duplicates, discarded:
//   D rows depend only on their own A row). Wave w owns kb in [8w, 8w+8),
//   4 n-tiles; B-frags loaded straight from fp32 kern (8 consecutive s =
//   contiguous 32 B/lane) with double-buffered prefetch, converted via the
//   same f2bf the validated prep kernel used. Cross-wave K-reduction
//   through padded LDS.
// ---------------------------------------------------------------------------
__global__ __launch_bounds__(512, 2) void fused_kernel(
        const float* __restrict__ x, const float* __restrict__ index,
        const float* __restrict__ kern, const float* __restrict__ bias,
        float* __restrict__ out)
{
    __shared__ __align__(16) u32 Ylds[8192];     // 32 KB: 8 bt x 2048 cs bf16
    __shared__ float w2[8][76];                  // doubled filter, per wave
    __shared__ float red[8][4][8][17];           // 17.4 KB reduction scratch

    const int tid  = threadIdx.x;
    const int w    = tid >> 6;              // wave 0..7 == row (bt & 7)
    const int lane = tid & 63;
    const int nm   = lane & 15;
    const int q    = lane >> 4;
    const int bt   = blockIdx.x * 8 + w;
    const int b    = bt >> 9;               // T2_ = 512

    // ======================= stage 1: interp =======================
    const float fidx = index[bt];
    const float flo  = floorf(fidx);
    const int   i0   = (int)flo;
    const float f    = fidx - flo;

    {   // filter: lane t computes w[t]; doubled into w2[w][0..71]
        const int t = lane;
        float wj;
        if (f <= 0.0f) {
            wj = (t == 0) ? 1.0f : 0.0f;
        } else {
            float spf = sinf(PI_F * f);              // sin(pi(t+f)) = (-1)^t sin(pi f)
            float a   = PI_F * ((float)t + f) * (1.0f / 64.0f);
            wj = ((t & 1) ? -spf : spf) * cosf(a) / (64.0f * sinf(a));
        }
        w2[w][t] = wj;
        if (t < 8) w2[w][64 + t] = wj;
    }
    // same-wave LDS write->read: compiler-inserted lgkmcnt, no barrier needed

    // 4 distinct A-frags (circulant W)
    short8 Afr[4];
    #pragma unroll
    for (int d = 0; d < 4; ++d) {
        const int o0 = (16 * d + q * 8 - nm) & 63;   // <= 63; +7 <= 70 < 76
        const float* wp = &w2[w][o0];
        union { u16 u[8]; short8 s; } cv;
        #pragma unroll
        for (int j = 0; j < 8; ++j) cv.u[j] = f2bf(wp[j]);
        Afr[d] = cv.s;
    }

    // 4 B-frags (X window) straight from global with clamp+mask
    short8 Bfr[2][2];
    #pragma unroll
    for (int kb = 0; kb < 2; ++kb)
        #pragma unroll
        for (int nt = 0; nt < 2; ++nt) {
            const int c = nt * 16 + nm;
            union { u16 u[8]; short8 s; } cv;
            #pragma unroll
            for (int j = 0; j < 8; ++j) {
                int pos = i0 - 32 + kb * 32 + q * 8 + j;
                int pc  = min(max(pos, 0), T1_ - 1);             // safe addr
                float v = x[(size_t)(b * T1_ + pc) * IC_ + c];
                v = ((unsigned)pos < (unsigned)T1_) ? v : 0.0f;  // zero-pad
                cv.u[j] = f2bf(v);
            }
            Bfr[kb][nt] = cv.s;
        }

    // 16 MFMA: acc[mt][nt] += Afr[(2kb-mt)&3] * Bfr[kb][nt]
    float4v acc[4][2];
    #pragma unroll
    for (int mt = 0; mt < 4; ++mt)
        #pragma unroll
        for (int nt = 0; nt < 2; ++nt)
            acc[mt][nt] = (float4v){0.f, 0.f, 0.f, 0.f};
    #pragma unroll
    for (int kb = 0; kb < 2; ++kb)
        #pragma unroll
        for (int mt = 0; mt < 4; ++mt) {
            const int d = (2 * kb - mt) & 3;
            #pragma unroll
            for (int nt = 0; nt < 2; ++nt)
                acc[mt][nt] = __builtin_amdgcn_mfma_f32_16x16x32_bf16(
                                  Afr[d], Bfr[kb][nt], acc[mt][nt], 0, 0, 0);
        }

    // Y -> LDS (swizzled, bf16). lane holds Y[bt][c*64 + mt*16 + q*4 + r]
    #pragma unroll
    for (int mt = 0; mt < 4; ++mt)
        #pragma unroll
        for (int nt = 0; nt < 2; ++nt) {
            const int c   = nt * 16 + nm;
            const int cs0 = c * 64 + mt * 16 + q * 4;
            const u32 wi  = (u32)((cs0 >> 3) * 32 + ((w ^ (c & 7)) << 2) + ((q & 1) << 1));
            const u32 d0  = (u32)f2bf(acc[mt][nt][0]) | ((u32)f2bf(acc[mt][nt][1]) << 16);
            const u32 d1  = (u32)f2bf(acc[mt][nt][2]) | ((u32)f2bf(acc[mt][nt][3]) << 16);
            *(uint2*)&Ylds[wi] = make_uint2(d0, d1);
        }

    // ======================= stage 2: gemm =========================
    // B base: o = nt*16 + nm, frag floats at kern[o*2048 + kb*32 + q*8 ..]
    const float4* bp = (const float4*)(kern + (size_t)nm * 2048 + w * 256 + q * 8);

    // issue first B tile before the barrier (latency hides under the sync)
    float4 Bb[2][4][2];
    #pragma unroll
    for (int nt = 0; nt < 4; ++nt) {
        Bb[0][nt][0] = bp[nt * 8192];
        Bb[0][nt][1] = bp[nt * 8192 + 1];
    }

    __syncthreads();                        // all Y rows visible

    const int rA = nm & 7;                  // A row (rows 8-15 duplicate 0-7)
    short8 Aa[2];
    {
        const int kb = w * 8;
        const u32 ab = (u32)(kb * 512 + q * 128 + ((rA ^ ((kb >> 1) & 7)) << 4));
        Aa[0] = *(const short8*)((const char*)Ylds + ab);
    }

    float4v a2[4];
    #pragma unroll
    for (int nt = 0; nt < 4; ++nt) a2[nt] = (float4v){0.f, 0.f, 0.f, 0.f};

    #pragma unroll
    for (int i = 0; i < 8; ++i) {
        const int cur = i & 1, nxt = cur ^ 1;
        if (i < 7) {                        // prefetch kb = w*8 + i + 1
            const int i1 = i + 1;
            const int fo = i1 * 8;          // float4 units = 32 floats
            #pragma unroll
            for (int nt = 0; nt < 4; ++nt) {
                Bb[nxt][nt][0] = bp[nt * 8192 + fo];
                Bb[nxt][nt][1] = bp[nt * 8192 + fo + 1];
            }
            const int kb = w * 8 + i1;
            const u32 ab = (u32)(kb * 512 + q * 128 + ((rA ^ ((kb >> 1) & 7)) << 4));
            Aa[nxt] = *(const short8*)((const char*)Ylds + ab);
        }
        #pragma unroll
        for (int nt = 0; nt < 4; ++nt) {
            union { u16 u[8]; short8 s; } cv;
            cv.u[0] = f2bf(Bb[cur][nt][0].x);
            cv.u[1] = f2bf(Bb[cur][nt][0].y);
            cv.u[2] = f2bf(Bb[cur][nt][0].z);
            cv.u[3] = f2bf(Bb[cur][nt][0].w);
            cv.u[4] = f2bf(Bb[cur][nt][1].x);
            cv.u[5] = f2bf(Bb[cur][nt][1].y);
            cv.u[6] = f2bf(Bb[cur][nt][1].z);
            cv.u[7] = f2bf(Bb[cur][nt][1].w);
            a2[nt] = __builtin_amdgcn_mfma_f32_16x16x32_bf16(Aa[cur], cv.s, a2[nt], 0, 0, 0);
        }
    }

    // cross-wave K reduction: D row = q*4+r (rows 0-7 real), col = nm
    if (q < 2) {
        #pragma unroll
        for (int nt = 0; nt < 4; ++nt)
            #pragma unroll
            for (int r = 0; r < 4; ++r)
                red[w][nt][q * 4 + r][nm] = a2[nt][r];
    }
    __syncthreads();

    // epilogue: thread (w, lane) -> out[blk*8 + w][lane]
    float s = bias[lane];
    #pragma unroll
    for (int ww = 0; ww < 8; ++ww)
        s += red[ww][q][w][nm];
    out[(size_t)bt * 64 + lane] = s;
}

// ---------------------------------------------------------------------------
extern "C" void kernel_launch(void* const* d_in, const int* in_sizes, int n_in,
                              void* d_out, int out_size, void* d_ws, size_t ws_size,
                              hipStream_t stream)
{
    const float* x     = (const float*)d_in[0];   // (4,4096,32) fp32
    const float* index = (const float*)d_in[1];   // (4,512) fp32
    const float* kern  = (const float*)d_in[2];   // (64,32,64) fp32
    const float* bias  = (const float*)d_in[3];   // (64,) fp32
    float* out = (float*)d_out;                   // (4,512,64) fp32
    (void)in_sizes; (void)n_in; (void)out_size; (void)d_ws; (void)ws_size;

    fused_kernel<<<dim3(B_ * T2_ / 8), dim3(512), 0, stream>>>(x, index, kern, bias, out);
}

// Round 4
// 71.924 us; speedup vs baseline: 1.0574x; 1.0574x over previous
//
#include <hip/hip_runtime.h>
#include <hip/hip_bf16.h>
#include <math.h>

#define B_   4
#define T1_  4096
#define T2_  512
#define IC_  32
#define OC_  64
#define KS_  64

typedef unsigned short u16;
typedef unsigned int   u32;
typedef __attribute__((ext_vector_type(8))) short  short8;   // 8 bf16 = 4 VGPRs
typedef __attribute__((ext_vector_type(4))) float  float4v;  // MFMA C/D frag

// RNE fp32 -> bf16 via the public HIP API; on gfx950 the backend
// pattern-matches pairs into v_cvt_pk_bf16_f32 (m240: scalar cast beats
// hand-written asm). Bit-identical to the validated bit-trick for finite
// inputs.
__device__ __forceinline__ u16 f2bf(float f) {
    __hip_bfloat16 h = __float2bfloat16(f);
    union { __hip_bfloat16 b; u16 u; } v; v.b = h;
    return v.u;
}

#define PI_F 3.14159265358979323846f

// ---------------------------------------------------------------------------
// K1: fused prep + MFMA-interp (R7-validated).
//   blocks [0,64):    prep — kernel (o,c,s) fp32 -> Bsz bf16 in MFMA B-frag
//                     order: Bsz[(cs>>3)*512 + o*8 + (cs&7)], cs = c*64+s.
//   blocks [64,576):  interp — 4 bt per block, one WAVE per bt.
//     Y_bt(64x32) = W(f)(64x64 circulant) @ Xwin(64x32) via 16x16x32 MFMA.
//     W[s][k] = w[(k-s)&63], w = closed-form fractional-delay filter
//     (irfft(rfft(kernel)*phase), incl. Nyquist cos term).
//     Circulant: A-frag(mt,kb) depends only on d=(2kb-mt)&3 -> 4 distinct
//     A-frags from doubled fp32 w2[] in LDS at lane offset (16d+q*8-m)&63.
//     B-frags (X) load straight from global with clamp+mask. No barriers.
// ---------------------------------------------------------------------------
__global__ __launch_bounds__(256) void prep_interp_kernel(
        const float* __restrict__ x, const float* __restrict__ index,
        const float* __restrict__ kern, u16* __restrict__ Y,
        u16* __restrict__ Bsz)
{
    __shared__ __align__(16) float w2[4][76];   // doubled filter, per wave

    const int tid = threadIdx.x;

    if (blockIdx.x < 64) {                  // ---- prep branch ----
        int gid = blockIdx.x * 256 + tid;   // 0..16383
        int o   = gid & 63;
        int cs8 = gid >> 6;                 // 0..255
        const float* p = kern + (size_t)o * 2048 + cs8 * 8;
        float4 a = *(const float4*)p;
        float4 b = *(const float4*)(p + 4);
        u16* q = Bsz + (size_t)cs8 * 512 + o * 8;
        *(ushort4*)(q)     = make_ushort4(f2bf(a.x), f2bf(a.y), f2bf(a.z), f2bf(a.w));
        *(ushort4*)(q + 4) = make_ushort4(f2bf(b.x), f2bf(b.y), f2bf(b.z), f2bf(b.w));
        return;
    }

    // ---- interp branch ----
    const int pb   = blockIdx.x - 64;       // 0..511 (XCD = pb%8)
    const int wv   = tid >> 6;              // wave 0..3
    const int lane = tid & 63;
    const int bt   = pb * 4 + wv;
    const int b    = bt >> 9;               // T2_ = 512

    const float fidx = index[bt];
    const float flo  = floorf(fidx);
    const int   i0   = (int)flo;
    const float f    = fidx - flo;

    // filter: lane t computes w[t]; doubled into w2[wv][0..71]
    {
        const int t = lane;
        float wj;
        if (f <= 0.0f) {
            wj = (t == 0) ? 1.0f : 0.0f;
        } else {
            float spf = sinf(PI_F * f);              // sin(pi(t+f)) = (-1)^t sin(pi f)
            float a   = PI_F * ((float)t + f) * (1.0f / 64.0f);
            wj = ((t & 1) ? -spf : spf) * cosf(a) / (64.0f * sinf(a));
        }
        w2[wv][t] = wj;
        if (t < 8) w2[wv][64 + t] = wj;              // w2[64+t] = w[t]
    }
    // same-wave LDS write->read: compiler-inserted lgkmcnt, no barrier needed

    const int nm = lane & 15;               // m (A), n (B), col (D)
    const int q  = lane >> 4;               // quad

    // ---- 4 distinct A-frags (circulant W) ----
    short8 Afr[4];
    #pragma unroll
    for (int d = 0; d < 4; ++d) {
        const int o0 = (16 * d + q * 8 - nm) & 63;   // <= 63; +7 <= 70 < 72
        const float* wp = &w2[wv][o0];
        union { u16 u[8]; short8 s; } cv;
        #pragma unroll
        for (int j = 0; j < 8; ++j) cv.u[j] = f2bf(wp[j]);
        Afr[d] = cv.s;
    }

    // ---- 4 B-frags (X window) straight from global ----
    short8 Bfr[2][2];
    #pragma unroll
    for (int kb = 0; kb < 2; ++kb) {
        #pragma unroll
        for (int nt = 0; nt < 2; ++nt) {
            const int c = nt * 16 + nm;
            union { u16 u[8]; short8 s; } cv;
            #pragma unroll
            for (int j = 0; j < 8; ++j) {
                int pos = i0 - 32 + kb * 32 + q * 8 + j;
                int pc  = min(max(pos, 0), T1_ - 1);             // safe addr
                float v = x[(size_t)(b * T1_ + pc) * IC_ + c];
                v = ((unsigned)pos < (unsigned)T1_) ? v : 0.0f;  // zero-pad
                cv.u[j] = f2bf(v);
            }
            Bfr[kb][nt] = cv.s;
        }
    }

    // ---- 16 MFMA: acc[mt][nt] += Afr[(2kb-mt)&3] * Bfr[kb][nt] ----
    float4v acc[4][2];
    #pragma unroll
    for (int mt = 0; mt < 4; ++mt)
        #pragma unroll
        for (int nt = 0; nt < 2; ++nt)
            acc[mt][nt] = (float4v){0.f, 0.f, 0.f, 0.f};
    #pragma unroll
    for (int kb = 0; kb < 2; ++kb)
        #pragma unroll
        for (int mt = 0; mt < 4; ++mt) {
            const int d = (2 * kb - mt) & 3;
            #pragma unroll
            for (int nt = 0; nt < 2; ++nt)
                acc[mt][nt] = __builtin_amdgcn_mfma_f32_16x16x32_bf16(
                                  Afr[d], Bfr[kb][nt], acc[mt][nt], 0, 0, 0);
        }

    // ---- store Y[bt][c*64 + s] bf16 ----
    #pragma unroll
    for (int mt = 0; mt < 4; ++mt)
        #pragma unroll
        for (int nt = 0; nt < 2; ++nt) {
            const int c = nt * 16 + nm;
            const int s = mt * 16 + q * 4;
            u32 d0 = (u32)f2bf(acc[mt][nt][0]) | ((u32)f2bf(acc[mt][nt][1]) << 16);
            u32 d1 = (u32)f2bf(acc[mt][nt][2]) | ((u32)f2bf(acc[mt][nt][3]) << 16);
            *(uint2*)(Y + (size_t)bt * 2048 + c * 64 + s) = make_uint2(d0, d1);
        }
}

// ---------------------------------------------------------------------------
// K2 (MFMA gemm v4): out[bt][o] = Y[bt,:] @ B[:,o] + bias[o].
// 128 blocks x 512 threads (8 waves). M=16 FULL rows (no zero-padding waste;
// halves aggregate Bsz L2 re-read vs M=8: 64 -> 32 MB).
// XCD-local bt map (producer: bt-quad pb ran on XCD pb%8):
//   pb(g,r16) = (g&7) + 8*(4*(g>>3) + (r16>>2)); bt = 4*pb + (r16&3).
// Wave w owns kb in [8w, 8w+8); FULL register prefetch then 32 MFMA.
// A-frag: lane(m+16q): Y[bt(m)][kb*32+q*8 ..+7]          (16B, L2-local)
// B-frag: lane(n+16q): Bsz[(kb*4+q)*512 + (nt*16+n)*8]   (16B, L2-hot)
// C/D   : lane L, reg r -> row (L>>4)*4+r, col L&15 (o within n-tile)
// ---------------------------------------------------------------------------
__global__ __launch_bounds__(512, 2) void gemm_kernel(const u16* __restrict__ Y,
                                                      const u16* __restrict__ Bsz,
                                                      const float* __restrict__ bias,
                                                      float* __restrict__ out)
{
    __shared__ float red[8][4][16][17];    // [wave][ntile][row][col], pad 17

    const int tid  = threadIdx.x;
    const int w    = tid >> 6;             // 0..7
    const int lane = tid & 63;
    const int nm   = lane & 15;
    const int q    = lane >> 4;
    const int g    = blockIdx.x;           // 0..127

    // bt for A-row nm (all 16 rows real)
    const int pbA = (g & 7) + 8 * (4 * (g >> 3) + (nm >> 2));
    const int btA = 4 * pbA + (nm & 3);

    const int kb0 = w * 8;
    const u16* aptr = Y   + (size_t)btA * 2048 + kb0 * 32 + q * 8;
    const u16* bptr = Bsz + (size_t)kb0 * 2048 + q * 512 + nm * 8;

    // ---- full prefetch: 8 A-frags + 32 B-frags in flight ----
    short8 a[8], b[8][4];
    #pragma unroll
    for (int i = 0; i < 8; ++i) {
        a[i] = *(const short8*)(aptr + i * 32);
        #pragma unroll
        for (int n = 0; n < 4; ++n)
            b[i][n] = *(const short8*)(bptr + (size_t)i * 2048 + n * 128);
    }

    float4v acc0 = {0,0,0,0}, acc1 = {0,0,0,0}, acc2 = {0,0,0,0}, acc3 = {0,0,0,0};
    #pragma unroll
    for (int i = 0; i < 8; ++i) {
        acc0 = __builtin_amdgcn_mfma_f32_16x16x32_bf16(a[i], b[i][0], acc0, 0, 0, 0);
        acc1 = __builtin_amdgcn_mfma_f32_16x16x32_bf16(a[i], b[i][1], acc1, 0, 0, 0);
        acc2 = __builtin_amdgcn_mfma_f32_16x16x32_bf16(a[i], b[i][2], acc2, 0, 0, 0);
        acc3 = __builtin_amdgcn_mfma_f32_16x16x32_bf16(a[i], b[i][3], acc3, 0, 0, 0);
    }

    // ---- cross-wave K reduction (all 16 D rows real) ----
    #pragma unroll
    for (int r = 0; r < 4; ++r) {
        const int row = q * 4 + r;
        red[w][0][row][nm] = acc0[r];
        red[w][1][row][nm] = acc1[r];
        red[w][2][row][nm] = acc2[r];
        red[w][3][row][nm] = acc3[r];
    }
    __syncthreads();

    // ---- epilogue: 1024 outputs (16 rows x 64 o), 2 per thread ----
    #pragma unroll
    for (int e = tid; e < 1024; e += 512) {
        const int row = e >> 6;            // 0..15
        const int o   = e & 63;
        float s = bias[o];
        #pragma unroll
        for (int ww = 0; ww < 8; ++ww)
            s += red[ww][o >> 4][row][o & 15];
        const int pbo = (g & 7) + 8 * (4 * (g >> 3) + (row >> 2));
        const int bto = 4 * pbo + (row & 3);
        out[(size_t)bto * 64 + o] = s;
    }
}

// ---------------------------------------------------------------------------
extern "C" void kernel_launch(void* const* d_in, const int* in_sizes, int n_in,
                              void* d_out, int out_size, void* d_ws, size_t ws_size,
                              hipStream_t stream)
{
    const float* x     = (const float*)d_in[0];   // (4,4096,32) fp32
    const float* index = (const float*)d_in[1];   // (4,512) fp32
    const float* kern  = (const float*)d_in[2];   // (64,32,64) fp32
    const float* bias  = (const float*)d_in[3];   // (64,) fp32
    float* out = (float*)d_out;                   // (4,512,64) fp32

    u16* Y   = (u16*)d_ws;                                      // 2048*2048 bf16 = 8 MB
    u16* Bsz = (u16*)((char*)d_ws + (size_t)8 * 1024 * 1024);   // 256 KB

    prep_interp_kernel<<<dim3(64 + B_ * T2_ / 4), dim3(256), 0, stream>>>(x, index, kern, Y, Bsz);
    gemm_kernel<<<dim3(128), dim3(512), 0, stream>>>(Y, Bsz, bias, out);
}